// Round 4
// baseline (603.629 us; speedup 1.0000x reference)
//
#include <hip/hip_runtime.h>
#include <hip/hip_bf16.h>
#include <math.h>

#define SEQ  2048
#define BATCH 8
#define NTOK (SEQ*BATCH)   // 16384 tokens

typedef __attribute__((ext_vector_type(8))) short short8v;
typedef __attribute__((ext_vector_type(4))) float f32x4;
typedef unsigned short u16;

__device__ __forceinline__ u16 f2bf(float f) {
    __hip_bfloat16 h = __float2bfloat16(f);
    return *reinterpret_cast<u16*>(&h);
}
__device__ __forceinline__ unsigned pack_bf2(float a, float b) {
    __hip_bfloat162 h = __float22bfloat162_rn(float2{a, b});
    return *reinterpret_cast<unsigned*>(&h);
}
// async global->LDS, 16B per lane; LDS dest must be wave-uniform base + lane*16
__device__ __forceinline__ void gl_lds16(const u16* g, u16* l) {
    __builtin_amdgcn_global_load_lds(
        (const __attribute__((address_space(1))) unsigned int*)g,
        (__attribute__((address_space(3))) unsigned int*)l, 16, 0, 0);
}

// ---------------------------------------------------------------------------
// 0a) weight convert + transpose:  W[K][N] fp32 -> Wt[N][K] bf16 (xscale)
// ---------------------------------------------------------------------------
struct WDescs {
    const float* src[14];
    int K[14];
    int N[14];
    long dst[14];
    float scale[14];
    int tstart[15];
};

__global__ __launch_bounds__(256) void convert_w_kernel(WDescs d, u16* __restrict__ WA) {
    __shared__ float tile[64][65];
    int blk = blockIdx.x;
    int di = 0;
    while (di < 13 && blk >= d.tstart[di + 1]) ++di;
    int t  = blk - d.tstart[di];
    int K  = d.K[di], N = d.N[di];
    int tn = N >> 6;
    int k0 = (t / tn) << 6, n0 = (t % tn) << 6;
    const float* src = d.src[di];
    float sc = d.scale[di];
    int tid = threadIdx.x;
    #pragma unroll
    for (int i = 0; i < 16; ++i) {
        int id = i * 256 + tid;
        int kk = id >> 6, nn = id & 63;
        tile[kk][nn] = src[(size_t)(k0 + kk) * N + n0 + nn];
    }
    __syncthreads();
    u16* dst = WA + d.dst[di];
    #pragma unroll
    for (int i = 0; i < 16; ++i) {
        int id = i * 256 + tid;
        int nn = id >> 6, kk = id & 63;
        dst[(size_t)(n0 + nn) * K + k0 + kk] = f2bf(tile[kk][nn] * sc);
    }
}

// 0b) bias arenas: qkv1 (1152) + dr2b zero-padded to 128 (at 1152..1279)
__global__ __launch_bounds__(256) void convert_bias_kernel(
    const float* qb1, const float* kb1, const float* vb1,
    const float* qb2, const float* kb2, const float* vb2,
    const float* dr2b, float* __restrict__ BA, float qs1, float qs2)
{
    int t = blockIdx.x * 256 + threadIdx.x;
    if      (t < 256)  BA[t] = qb1[t] * qs1;
    else if (t < 512)  BA[t] = kb1[t - 256];
    else if (t < 768)  BA[t] = vb1[t - 512];
    else if (t < 896)  BA[t] = qb2[t - 768] * qs2;
    else if (t < 1024) BA[t] = kb2[t - 896];
    else if (t < 1152) BA[t] = vb2[t - 1024];
    else if (t < 1216) BA[t] = dr2b[t - 1152];
    else if (t < 1280) BA[t] = 0.f;
}

// ---------------------------------------------------------------------------
// 1) h = x + positional encoding (exp2/native trig)
// ---------------------------------------------------------------------------
__global__ __launch_bounds__(256) void add_pe_kernel(const float* __restrict__ x,
                                                     float* __restrict__ h,
                                                     u16* __restrict__ hb) {
    int idx = blockIdx.x * 256 + threadIdx.x;     // over SEQ*256
    int s = idx >> 8;
    int d = idx & 255;
    // 1/10000^(d/256) = exp2(-d * log2(10000)/256)
    float inv = exp2f((float)d * -0.0519051264732f);
    float ang = (float)s * inv;
    float pe  = (d & 1) ? __cosf(ang) : __sinf(ang);
    #pragma unroll
    for (int b = 0; b < BATCH; ++b) {
        size_t g = ((size_t)(b * SEQ + s) << 8) + d;
        float v = x[g] + pe;
        h[g]  = v;
        hb[g] = f2bf(v);
    }
}

// ---------------------------------------------------------------------------
// 2) bf16 MFMA GEMM, m97 structure: 128x128 tile, BK=64, single 32KB LDS
//    buffer, global_load_lds(16B) staging with pre-swizzled global source,
//    XOR-swizzled ds_read_b128 fragments.
// ---------------------------------------------------------------------------
template<int RELU, int WF32, int WBF16>
__global__ __launch_bounds__(256) void gemm_bf16_kernel(
    const u16* __restrict__ A, const u16* __restrict__ Bt,
    const float* __restrict__ bias, float* __restrict__ Cf,
    u16* __restrict__ Cb, int N, int K)
{
    __shared__ u16 As[128 * 64];
    __shared__ u16 Bs[128 * 64];
    const int tid  = threadIdx.x;
    const int lane = tid & 63;
    const int c    = lane & 15, g = lane >> 4;
    const int w    = tid >> 6;
    const int wr   = w >> 1, wc = w & 1;
    const size_t bm = (size_t)blockIdx.y * 128;
    const size_t bn = (size_t)blockIdx.x * 128;

    f32x4 acc[4][4];
    #pragma unroll
    for (int i = 0; i < 4; ++i)
        #pragma unroll
        for (int j = 0; j < 4; ++j) acc[i][j] = (f32x4){0.f, 0.f, 0.f, 0.f};

    const int nt = K >> 6;
    for (int t = 0; t < nt; ++t) {
        // stage: LDS[row][blk] = A[row][blk ^ (row&7)] (pre-swizzled source)
        #pragma unroll
        for (int j = 0; j < 4; ++j) {
            int cid = j * 256 + tid;
            int row = cid >> 3, blk = cid & 7;
            int sof = (blk ^ (row & 7)) * 8;
            gl_lds16(&A [(bm + row) * K + t * 64 + sof], &As[cid * 8]);
            gl_lds16(&Bt[(bn + row) * K + t * 64 + sof], &Bs[cid * 8]);
        }
        __syncthreads();
        #pragma unroll
        for (int ks2 = 0; ks2 < 2; ++ks2) {
            short8v af[4], bfr[4];
            #pragma unroll
            for (int am = 0; am < 4; ++am) {
                int r = wr * 64 + am * 16 + c;
                af[am] = *(const short8v*)&As[r * 64 + (((ks2 * 4 + g) ^ (r & 7)) * 8)];
            }
            #pragma unroll
            for (int bn_ = 0; bn_ < 4; ++bn_) {
                int r = wc * 64 + bn_ * 16 + c;
                bfr[bn_] = *(const short8v*)&Bs[r * 64 + (((ks2 * 4 + g) ^ (r & 7)) * 8)];
            }
            #pragma unroll
            for (int am = 0; am < 4; ++am)
                #pragma unroll
                for (int bn_ = 0; bn_ < 4; ++bn_)
                    acc[am][bn_] = __builtin_amdgcn_mfma_f32_16x16x32_bf16(
                                       af[am], bfr[bn_], acc[am][bn_], 0, 0, 0);
        }
        __syncthreads();
    }

    float bv[4];
    #pragma unroll
    for (int bn_ = 0; bn_ < 4; ++bn_) bv[bn_] = bias[bn + wc * 64 + bn_ * 16 + c];
    #pragma unroll
    for (int am = 0; am < 4; ++am) {
        #pragma unroll
        for (int bn_ = 0; bn_ < 4; ++bn_) {
            #pragma unroll
            for (int i = 0; i < 4; ++i) {
                size_t row = bm + wr * 64 + am * 16 + 4 * g + i;
                size_t col = bn + wc * 64 + bn_ * 16 + c;
                float v = acc[am][bn_][i] + bv[bn_];
                if (RELU) v = fmaxf(v, 0.f);
                if (WF32)  Cf[row * N + col] = v;
                if (WBF16) Cb[row * N + col] = f2bf(v);
            }
        }
    }
}

// ---------------------------------------------------------------------------
// 3) LayerNorm(a + r) * g + b  ->  fp32 (+ optional bf16)
// ---------------------------------------------------------------------------
template<int D, int WBF>
__global__ __launch_bounds__(256) void ln_residual_kernel(
    const float* __restrict__ a, const float* __restrict__ r,
    const float* __restrict__ g, const float* __restrict__ bb,
    float* __restrict__ out, u16* __restrict__ outb)
{
    const int N = D >> 6;
    int wave = threadIdx.x >> 6;
    int lane = threadIdx.x & 63;
    size_t token = (size_t)blockIdx.x * 4 + wave;
    const float* ar = a + token * D;
    const float* rr = r + token * D;

    float xv[N];
    float s = 0.f;
    #pragma unroll
    for (int i = 0; i < N; ++i) {
        int d = lane + (i << 6);
        xv[i] = ar[d] + rr[d];
        s += xv[i];
    }
    #pragma unroll
    for (int off = 1; off < 64; off <<= 1) s += __shfl_xor(s, off);
    float mean = s * (1.0f / D);
    float vs = 0.f;
    #pragma unroll
    for (int i = 0; i < N; ++i) { float d0 = xv[i] - mean; vs += d0 * d0; }
    #pragma unroll
    for (int off = 1; off < 64; off <<= 1) vs += __shfl_xor(vs, off);
    float inv = 1.0f / sqrtf(vs * (1.0f / D) + 1e-5f);
    #pragma unroll
    for (int i = 0; i < N; ++i) {
        int d = lane + (i << 6);
        float v = (xv[i] - mean) * inv * g[d] + bb[d];
        out[token * D + d] = v;
        if (WBF) outb[token * D + d] = f2bf(v);
    }
}

// ---------------------------------------------------------------------------
// 4) bf16-MFMA flash attention v2.
//    - packed QKV [T,3D] bf16 in, bf16 out; p = exp2(s) (no running max)
//    - Ks linear [64][32] (64B rows, conflict-free), staged via global_load_lds
//    - Vt/Pb: [row][64] u16, 128B rows, block-XOR swizzle
//      phys_blk = blk ^ vkey(row), vkey = (row&7) ^ ((row&8)>>1)
//    - single barrier/tile, double-buffered K/V, T14 split V staging
//    - XCD-aware remap: all 16 q-blocks of one (b,h) share H%8
// ---------------------------------------------------------------------------
template<int HD>
__global__ __launch_bounds__(256) void flash_mfma_kernel(
    const u16* __restrict__ QKV, u16* __restrict__ Og)
{
    constexpr int D   = 8 * HD;
    constexpr int SD  = 3 * D;
    constexpr int NDH = HD / 16;

    __shared__ u16 Ks[2][64 * 32];
    __shared__ u16 Vt[2][NDH * 16 * 64];
    __shared__ u16 Pb[64 * 64];

    const int tid  = threadIdx.x;
    const int w    = tid >> 6;
    const int lane = tid & 63;
    const int c    = lane & 15;
    const int g    = lane >> 4;

    const int H    = blockIdx.x + (blockIdx.y << 4);   // gridDim.x == 16
    const int bh   = H & 63;                           // same bh -> same H%8 -> same XCD
    const int qblk = H >> 6;
    const int b = bh >> 3, hh = bh & 7;
    const size_t qvbase = (size_t)b * SEQ * SD + (size_t)hh * HD;
    const size_t obase  = (size_t)b * SEQ * D  + (size_t)hh * HD;
    const int qbase = qblk * 128;

    // Q fragments (scale pre-folded into weights)
    short8v qf[2];
    #pragma unroll
    for (int qb = 0; qb < 2; ++qb) {
        if (HD == 16 && g >= 2) {
            short8v z = {0, 0, 0, 0, 0, 0, 0, 0};
            qf[qb] = z;
        } else {
            int qrow = qbase + w * 32 + qb * 16 + c;
            qf[qb] = *(const short8v*)&QKV[qvbase + (size_t)qrow * SD + 8 * g];
        }
    }

    f32x4 oacc[2][NDH];
    float lreg[2][4];
    #pragma unroll
    for (int qb = 0; qb < 2; ++qb) {
        #pragma unroll
        for (int dh = 0; dh < NDH; ++dh) oacc[qb][dh] = (f32x4){0.f, 0.f, 0.f, 0.f};
        #pragma unroll
        for (int i = 0; i < 4; ++i) lreg[qb][i] = 0.f;
    }

    const int skey = tid >> 2;              // 0..63
    const int sch  = (tid & 3) * 8;         // 0,8,16,24
    const int spos = ((skey >> 5) << 5) + 2 * (skey & 15) + ((skey >> 4) & 1);
    const int squad = spos >> 3, soff = spos & 7;
    const bool vstager = !(HD == 16 && sch >= 16);
    const int vkc = (c & 7) ^ ((c & 8) >> 1);

    // ---- prologue: stage tile 0 ----
    gl_lds16(&QKV[qvbase + (size_t)skey * SD + D + sch], &Ks[0][tid * 8]);
    if (vstager) {
        short8v v0 = *(const short8v*)&QKV[qvbase + (size_t)skey * SD + 2 * D + sch];
        #pragma unroll
        for (int i = 0; i < 8; ++i) {
            int row = sch + i;
            int vk = (row & 7) ^ ((row & 8) >> 1);
            Vt[0][row * 64 + ((squad ^ vk) << 3) + soff] = (u16)v0[i];
        }
    }
    __syncthreads();

    int buf = 0;
    const int NT = SEQ / 64;
    for (int t = 0; t < NT; ++t) {
        short8v vv = {0, 0, 0, 0, 0, 0, 0, 0};
        const bool pre = (t + 1 < NT);
        if (pre) {   // issue next-tile loads early (T14): K direct-to-LDS, V to regs
            const size_t nb = qvbase + (size_t)((t + 1) * 64 + skey) * SD;
            if (vstager) vv = *(const short8v*)&QKV[nb + 2 * D + sch];
            gl_lds16(&QKV[nb + D + sch], &Ks[buf ^ 1][tid * 8]);
        }

        // fragments for this tile (shared by both q-blocks)
        short8v kf[4];
        #pragma unroll
        for (int kh = 0; kh < 4; ++kh)
            kf[kh] = *(const short8v*)&Ks[buf][(16 * kh + c) * 32 + 8 * g];
        short8v vfr[NDH][2];
        #pragma unroll
        for (int dh = 0; dh < NDH; ++dh) {
            vfr[dh][0] = *(const short8v*)&Vt[buf][(16 * dh + c) * 64 + ((g ^ vkc) << 3)];
            vfr[dh][1] = *(const short8v*)&Vt[buf][(16 * dh + c) * 64 + (((4 + g) ^ vkc) << 3)];
        }

        #pragma unroll
        for (int qb = 0; qb < 2; ++qb) {
            f32x4 s[4];
            #pragma unroll
            for (int kh = 0; kh < 4; ++kh)
                s[kh] = __builtin_amdgcn_mfma_f32_16x16x32_bf16(
                            qf[qb], kf[kh], (f32x4){0.f, 0.f, 0.f, 0.f}, 0, 0, 0);

            #pragma unroll
            for (int i = 0; i < 4; ++i) {
                float p0 = exp2f(s[0][i]);
                float p1 = exp2f(s[1][i]);
                float p2 = exp2f(s[2][i]);
                float p3 = exp2f(s[3][i]);
                lreg[qb][i] += (p0 + p1) + (p2 + p3);
                int rr = 4 * g + i;
                int pk = (rr & 7) ^ ((rr & 8) >> 1);
                int base = (w * 16 + rr) * 64 + 2 * (c & 3);
                *(unsigned*)&Pb[base + (((c >> 2) ^ pk) << 3)]       = pack_bf2(p0, p1);
                *(unsigned*)&Pb[base + ((((c >> 2) + 4) ^ pk) << 3)] = pack_bf2(p2, p3);
            }

            short8v pf0 = *(const short8v*)&Pb[(w * 16 + c) * 64 + ((g ^ vkc) << 3)];
            short8v pf1 = *(const short8v*)&Pb[(w * 16 + c) * 64 + (((4 + g) ^ vkc) << 3)];
            #pragma unroll
            for (int dh = 0; dh < NDH; ++dh) {
                oacc[qb][dh] = __builtin_amdgcn_mfma_f32_16x16x32_bf16(
                                   pf0, vfr[dh][0], oacc[qb][dh], 0, 0, 0);
                oacc[qb][dh] = __builtin_amdgcn_mfma_f32_16x16x32_bf16(
                                   pf1, vfr[dh][1], oacc[qb][dh], 0, 0, 0);
            }
        }

        // late half of T14 split: vmcnt-wait + scatter write hidden under compute
        if (pre && vstager) {
            #pragma unroll
            for (int i = 0; i < 8; ++i) {
                int row = sch + i;
                int vk = (row & 7) ^ ((row & 8) >> 1);
                Vt[buf ^ 1][row * 64 + ((squad ^ vk) << 3) + soff] = (u16)vv[i];
            }
        }
        __syncthreads();
        buf ^= 1;
    }

    // ---- epilogue: O = acc / l ----
    #pragma unroll
    for (int qb = 0; qb < 2; ++qb) {
        #pragma unroll
        for (int i = 0; i < 4; ++i) {
            float li = lreg[qb][i];
            li += __shfl_xor(li, 1);
            li += __shfl_xor(li, 2);
            li += __shfl_xor(li, 4);
            li += __shfl_xor(li, 8);
            float inv = 1.0f / li;
            int qrow = qbase + w * 32 + qb * 16 + 4 * g + i;
            #pragma unroll
            for (int dh = 0; dh < NDH; ++dh)
                Og[obase + (size_t)qrow * D + 16 * dh + c] = f2bf(oacc[qb][dh][i] * inv);
        }
    }
}

// ---------------------------------------------------------------------------
// 5) max over sequence dim:  in [B, S, 128-stride] (first 64 cols) -> [B, 64]
// ---------------------------------------------------------------------------
__global__ __launch_bounds__(256) void maxpool_kernel(const float* __restrict__ in,
                                                      float* __restrict__ out) {
    __shared__ float red[4][64];
    int b = blockIdx.x, d = threadIdx.x & 63, st = threadIdx.x >> 6;
    float m = -INFINITY;
    for (int s = st * (SEQ / 4); s < (st + 1) * (SEQ / 4); ++s)
        m = fmaxf(m, in[((size_t)b * SEQ + s) * 128 + d]);
    red[st][d] = m;
    __syncthreads();
    if (st == 0) {
        m = fmaxf(fmaxf(red[0][d], red[1][d]), fmaxf(red[2][d], red[3][d]));
        out[b * 64 + d] = m;
    }
}

// ---------------------------------------------------------------------------
// 6) head
// ---------------------------------------------------------------------------
__global__ __launch_bounds__(256) void head_kernel(
    const float* __restrict__ pooled,
    const float* __restrict__ w3, const float* __restrict__ b3,
    const float* __restrict__ w4, const float* __restrict__ b4,
    float* __restrict__ out)
{
    __shared__ float t[8][32];
    int tid = threadIdx.x;
    {
        int b = tid >> 5, j = tid & 31;
        float s = b3[j];
        #pragma unroll
        for (int k = 0; k < 64; ++k) s = fmaf(pooled[b * 64 + k], w3[k * 32 + j], s);
        t[b][j] = s;
    }
    __syncthreads();
    if (tid < 8 * 14) {
        int b = tid / 14, j = tid % 14;
        float s = b4[j];
        #pragma unroll
        for (int k = 0; k < 32; ++k) s = fmaf(t[b][k], w4[k * 14 + j], s);
        out[b * 14 + j] = s;
    }
}

// ---------------------------------------------------------------------------
extern "C" void kernel_launch(void* const* d_in, const int* in_sizes, int n_in,
                              void* d_out, int out_size, void* d_ws, size_t ws_size,
                              hipStream_t stream) {
    const float* x     = (const float*)d_in[0];
    const float* qw1   = (const float*)d_in[1];
    const float* qb1   = (const float*)d_in[2];
    const float* kw1   = (const float*)d_in[3];
    const float* kb1   = (const float*)d_in[4];
    const float* vw1   = (const float*)d_in[5];
    const float* vb1   = (const float*)d_in[6];
    const float* ow1   = (const float*)d_in[7];
    const float* ob1   = (const float*)d_in[8];
    const float* f1w1  = (const float*)d_in[9];
    const float* f1b1  = (const float*)d_in[10];
    const float* f2w1  = (const float*)d_in[11];
    const float* f2b1  = (const float*)d_in[12];
    const float* ln1g1 = (const float*)d_in[13];
    const float* ln1b1 = (const float*)d_in[14];
    const float* ln2g1 = (const float*)d_in[15];
    const float* ln2b1 = (const float*)d_in[16];
    const float* qw2   = (const float*)d_in[17];
    const float* qb2   = (const float*)d_in[18];
    const float* kw2   = (const float*)d_in[19];
    const float* kb2   = (const float*)d_in[20];
    const float* vw2   = (const float*)d_in[21];
    const float* vb2   = (const float*)d_in[22];
    const float* ow2   = (const float*)d_in[23];
    const float* ob2   = (const float*)d_in[24];
    const float* f1w2  = (const float*)d_in[25];
    const float* f1b2  = (const float*)d_in[26];
    const float* f2w2  = (const float*)d_in[27];
    const float* f2b2  = (const float*)d_in[28];
    const float* ln1g2 = (const float*)d_in[29];
    const float* ln1b2 = (const float*)d_in[30];
    const float* ln2g2 = (const float*)d_in[31];
    const float* ln2b2 = (const float*)d_in[32];
    const float* dr1w  = (const float*)d_in[33];
    const float* dr1b  = (const float*)d_in[34];
    const float* dr2w  = (const float*)d_in[35];
    const float* dr2b  = (const float*)d_in[36];
    const float* dr3w  = (const float*)d_in[37];
    const float* dr3b  = (const float*)d_in[38];
    const float* dr4w  = (const float*)d_in[39];
    const float* dr4b  = (const float*)d_in[40];

    const size_t T = NTOK;
    float* F1 = (float*)d_ws;            // [T,256] fp32 residual stream
    float* F2 = F1 + T * 256;            // [T,256] fp32 scratch
    u16*   E1 = (u16*)(F2 + T * 256);    // [T,256] bf16
    u16*   E2 = E1 + T * 256;            // [T,256] bf16
    u16*   E3 = E2 + T * 256;            // [T,256] bf16
    u16*   Dq = E3 + T * 256;            // [T,1024] bf16 (qkv-packed / ff scratch)
    u16*   WA = Dq + T * 1024;           // bf16 weight arena
    float* BA = (float*)(WA + 1048576);  // bias arena (1280 floats)

    const float QS1 = 0.25503488f;       // log2e / sqrt(32)
    const float QS2 = 0.36067376f;       // log2e / sqrt(16)

    WDescs wd;
    const float* srcs[14] = {qw1, kw1, vw1, ow1, f1w1, f2w1, dr1w,
                             qw2, kw2, vw2, ow2, f1w2, f2w2, dr2w};
    int Ks_[14]  = {256, 256, 256, 256, 256, 1024, 256, 128, 128, 128, 128, 128, 512, 128};
    int Ns_[14]  = {256, 256, 256, 256, 1024, 256, 128, 128, 128, 128, 128, 512, 128, 64};
    long dsts[14] = {0, 65536, 131072, 196608, 262144, 524288, 786432,
                     819200, 835584, 851968, 868352, 884736, 950272, 1015808};
    float scs[14] = {QS1, 1.f, 1.f, 1.f, 1.f, 1.f, 1.f, QS2, 1.f, 1.f, 1.f, 1.f, 1.f, 1.f};
    int tst[15] = {0, 16, 32, 48, 64, 128, 192, 200, 204, 208, 212, 216, 232, 248, 250};
    for (int i = 0; i < 14; ++i) {
        wd.src[i] = srcs[i]; wd.K[i] = Ks_[i]; wd.N[i] = Ns_[i];
        wd.dst[i] = dsts[i]; wd.scale[i] = scs[i];
    }
    for (int i = 0; i < 15; ++i) wd.tstart[i] = tst[i];

    const dim3 blk(256);

    convert_w_kernel<<<250, blk, 0, stream>>>(wd, WA);
    convert_bias_kernel<<<5, blk, 0, stream>>>(qb1, kb1, vb1, qb2, kb2, vb2, dr2b, BA, QS1, QS2);

    add_pe_kernel<<<SEQ, blk, 0, stream>>>(x, F1, E1);

    // ================= encoder 1 (d=256, ff=1024, hd=32) =================
    gemm_bf16_kernel<0,0,1><<<dim3(6, 128), blk, 0, stream>>>(E1, WA + 0,      BA,   nullptr, Dq, 768, 256);
    flash_mfma_kernel<32><<<dim3(16, 64), blk, 0, stream>>>(Dq, E2);
    gemm_bf16_kernel<0,1,0><<<dim3(2, 128), blk, 0, stream>>>(E2, WA + 196608, ob1,  F2, nullptr, 256, 256);
    ln_residual_kernel<256,1><<<NTOK / 4, blk, 0, stream>>>(F2, F1, ln1g1, ln1b1, F1, E1);
    gemm_bf16_kernel<1,0,1><<<dim3(8, 128), blk, 0, stream>>>(E1, WA + 262144, f1b1, nullptr, Dq, 1024, 256);
    gemm_bf16_kernel<0,1,0><<<dim3(2, 128), blk, 0, stream>>>(Dq, WA + 524288, f2b1, F2, nullptr, 256, 1024);
    ln_residual_kernel<256,1><<<NTOK / 4, blk, 0, stream>>>(F2, F1, ln2g1, ln2b1, F1, E1);

    // ---- 256 -> 128 ----
    gemm_bf16_kernel<0,1,1><<<dim3(1, 128), blk, 0, stream>>>(E1, WA + 786432, dr1b, F2, E2, 128, 256);

    // ================= encoder 2 (d=128, ff=512, hd=16) =================
    gemm_bf16_kernel<0,0,1><<<dim3(3, 128), blk, 0, stream>>>(E2, WA + 819200, BA + 768, nullptr, Dq, 384, 128);
    flash_mfma_kernel<16><<<dim3(16, 64), blk, 0, stream>>>(Dq, E3);
    gemm_bf16_kernel<0,1,0><<<dim3(1, 128), blk, 0, stream>>>(E3, WA + 868352, ob2,  F1, nullptr, 128, 128);
    ln_residual_kernel<128,1><<<NTOK / 4, blk, 0, stream>>>(F1, F2, ln1g2, ln1b2, F2, E1);
    gemm_bf16_kernel<1,0,1><<<dim3(4, 128), blk, 0, stream>>>(E1, WA + 884736, f1b2, nullptr, Dq, 512, 128);
    gemm_bf16_kernel<0,1,0><<<dim3(1, 128), blk, 0, stream>>>(Dq, WA + 950272, f2b2, F1, nullptr, 128, 512);
    ln_residual_kernel<128,1><<<NTOK / 4, blk, 0, stream>>>(F1, F2, ln2g2, ln2b2, F2, E1);

    // ---- 128 -> 64 (bf16 MFMA, N padded to 128), pool, head ----
    gemm_bf16_kernel<0,1,0><<<dim3(1, 128), blk, 0, stream>>>(E1, WA + 1015808, BA + 1152, F1, nullptr, 128, 128);
    maxpool_kernel<<<BATCH, blk, 0, stream>>>(F1, F2);
    head_kernel<<<1, blk, 0, stream>>>(F2, dr3w, dr3b, dr4w, dr4b, (float*)d_out);
}